// Round 12
// baseline (158.000 us; speedup 1.0000x reference)
//
#include <hip/hip_runtime.h>

#define DIMC 1024
#define HEADS 16
#define HD 64
#define BATCH 2
#define SEQ 1024
#define NQKV 3072

typedef _Float16 f16;
typedef _Float16 half8 __attribute__((ext_vector_type(8)));
typedef _Float16 half4v __attribute__((ext_vector_type(4)));
typedef float floatx4 __attribute__((ext_vector_type(4)));

__device__ __forceinline__ void gld16(const void* g, void* l) {
  __builtin_amdgcn_global_load_lds((const __attribute__((address_space(1))) void*)g,
                                   (__attribute__((address_space(3))) void*)l, 16, 0, 0);
}

__device__ __forceinline__ unsigned sadU8(unsigned a, unsigned b, unsigned c) {
#if __has_builtin(__builtin_amdgcn_sad_u8)
  return __builtin_amdgcn_sad_u8(a, b, c);
#else
  unsigned d;
  asm("v_sad_u8 %0, %1, %2, %3" : "=v"(d) : "v"(a), "v"(b), "v"(c));
  return d;
#endif
}

// ---------------- f32 -> f16 casts (x, qkv_w, proj_w), 4 float4/thread ----------------
__global__ __launch_bounds__(256) void cvt_kernel(
    const float* __restrict__ x, const float* __restrict__ wq, const float* __restrict__ wp,
    f16* __restrict__ x16, f16* __restrict__ wq16, f16* __restrict__ wp16)
{
  int bid = blockIdx.x;
  const float* src; f16* dst; int base;
  if (bid < 512)        { src = x;  dst = x16;  base = bid; }
  else if (bid < 1280)  { src = wq; dst = wq16; base = bid - 512; }
  else                  { src = wp; dst = wp16; base = bid - 1280; }
  long long i0 = (long long)base*1024 + threadIdx.x;
#pragma unroll
  for (int k2 = 0; k2 < 4; ++k2) {
    long long i = i0 + k2*256;   // float4 index, coalesced
    float4 v = ((const float4*)src)[i];
    half4v h; h[0]=(f16)v.x; h[1]=(f16)v.y; h[2]=(f16)v.z; h[3]=(f16)v.w;
    *(half4v*)(dst + i*4) = h;
  }
}

// ---------------- TM x TN f16 MFMA GEMM (BK-deep K-tiles), C = A * Bw^T + bias ----
// MODE 0: QKV -> q8/k8 (u8 quant, [b,h,s,d]) and vT (f16, [b,h,d,s])
// MODE 1: proj -> f32 out [t, f]
template<int TM, int TN, int BK, int MW, int MODE>
__global__ __launch_bounds__(256, MW) void gemm_kernel(
    const f16* __restrict__ A, const f16* __restrict__ Bw, const float* __restrict__ bias,
    unsigned char* __restrict__ q8, unsigned char* __restrict__ k8, f16* __restrict__ vT,
    float* __restrict__ outp, int K)
{
  constexpr int MT = TM / 32;   // m-subtiles per wave
  constexpr int NT = TN / 32;   // n-subtiles per wave
  constexpr int G  = BK / 8;    // 16B groups per LDS row
  __shared__ f16 As[TM*BK];
  __shared__ f16 Bs[TN*BK];
  const int tid = threadIdx.x;
  const int wave = tid >> 6, lane = tid & 63;
  const int lq = lane >> 4, li = lane & 15;
  const int m0 = blockIdx.y * TM, n0 = blockIdx.x * TN;
  const int wm = (wave & 1) * (TM/2), wn = (wave >> 1) * (TN/2);
  floatx4 acc[MT][NT] = {};

  const int kIters = K / BK;
  for (int kt = 0; kt < kIters; ++kt) {
    __syncthreads();
#pragma unroll
    for (int r = 0; r < TM*BK/2048; ++r) {
      int slot = r*256 + tid;
      int row = slot / G, c = slot % G, g = c ^ (row & (G-1));
      gld16(A + (size_t)(m0+row)*K + kt*BK + g*8, As + slot*8);
    }
#pragma unroll
    for (int r = 0; r < TN*BK/2048; ++r) {
      int slot = r*256 + tid;
      int row = slot / G, c = slot % G, g = c ^ (row & (G-1));
      gld16(Bw + (size_t)(n0+row)*K + kt*BK + g*8, Bs + slot*8);
    }
    __syncthreads();
#pragma unroll
    for (int ks = 0; ks < BK/32; ++ks) {
      half8 af[MT], bf[NT];
      int kc = ks*4 + lq;
#pragma unroll
      for (int t = 0; t < MT; ++t) {
        int am = wm + t*16 + li;
        af[t] = *(const half8*)&As[am*BK + (kc ^ (am & (G-1)))*8];
      }
#pragma unroll
      for (int t = 0; t < NT; ++t) {
        int bn = wn + t*16 + li;
        bf[t] = *(const half8*)&Bs[bn*BK + (kc ^ (bn & (G-1)))*8];
      }
#pragma unroll
      for (int mt = 0; mt < MT; ++mt)
#pragma unroll
        for (int nt = 0; nt < NT; ++nt)
          acc[mt][nt] = __builtin_amdgcn_mfma_f32_16x16x32_f16(af[mt], bf[nt], acc[mt][nt], 0, 0, 0);
    }
  }

#pragma unroll
  for (int mt = 0; mt < MT; ++mt) {
#pragma unroll
    for (int nt = 0; nt < NT; ++nt) {
      int f = n0 + wn + nt*16 + li;                 // output feature (col, from B)
      float bb = bias[f];
      if (MODE == 0) {
        int which = f >> 10, cc = f & 1023, h = cc >> 6, d = cc & 63;
        int t0 = m0 + wm + mt*16 + lq*4;            // token (row, from A), 4 consecutive
        int b = t0 >> 10, s0 = t0 & 1023;
        if (which == 2) {
          half4v hv;
#pragma unroll
          for (int r = 0; r < 4; ++r) hv[r] = (f16)(acc[mt][nt][r] + bb);
          *(half4v*)&vT[((size_t)((b*HEADS + h)*HD + d))*SEQ + s0] = hv;
        } else {
          unsigned char* dst = (which == 0) ? q8 : k8;
#pragma unroll
          for (int r = 0; r < 4; ++r) {
            float v = acc[mt][nt][r] + bb;
            int u = (int)floorf(v * 16.0f + 128.5f);
            u = u < 0 ? 0 : (u > 255 ? 255 : u);
            dst[((size_t)((b*HEADS + h)*SEQ + s0 + r))*HD + d] = (unsigned char)u;
          }
        }
      } else {
#pragma unroll
        for (int r = 0; r < 4; ++r) {
          int t = m0 + wm + mt*16 + lq*4 + r;
          outp[(size_t)t*DIMC + f] = acc[mt][nt][r] + bb;
        }
      }
    }
  }
}

// ---------------- Laplacian attention + depthwise conv, y16 out ----------------
// R12: R11 loop structure (3 barriers, vTs in LDS) retiled to 32-row q-tiles:
//  - grid 1024 blocks = 4/CU (512 was the occupancy cap, not LDS)
//  - SAD mapping iL=tid&7: 4 rows x 4 keys/thread -> same 16 SADs per b128 read
//  - k8s store-side group swizzle (R5-verified) -> conflict-free k broadcasts
//  - sfrag 8KB, half4v A-frag writes (R5-verified addressing)
//  LDS 39.3KB, VGPR ~80 -> 4 blocks/CU resident.
__global__ __launch_bounds__(256, 3) void attn_kernel(
    const unsigned char* __restrict__ q8g, const unsigned char* __restrict__ k8g,
    const f16* __restrict__ vTg, const float* __restrict__ dwcw, const float* __restrict__ dwcb,
    f16* __restrict__ y16)
{
  __shared__ unsigned char q8s[32*64];   //  2KB
  __shared__ unsigned char k8s[128*64];  //  8KB (group-swizzled)
  __shared__ f16 vTs[64*128];            // 16KB  [d][j] swizzled
  __shared__ f16 sfrag[8*64*8];          //  8KB  scores in MFMA A-frag layout
  __shared__ float rowsum[32];           //  128B
  __shared__ f16 vconv[64*34];           //  4.25KB v window for conv

  const int tid = threadIdx.x;
  const int bh = blockIdx.y;             // b*16+h
  const int i0 = blockIdx.x * 32;
  const int lane = tid & 63, wave = tid >> 6;
  const int lq = lane >> 4, li = lane & 15;
  const int iL = tid & 7, jt = tid >> 3; // 4 rows x 4 keys per thread; jt>>3 == wave
  const int mtw = wave & 1, dh = wave >> 1;

  if (tid < 32) rowsum[tid] = 1e-6f;     // EPS folded into init

  // stage q tile: 32 rows x 64B (waves 0,1 — wave-uniform branch)
  if (wave < 2)
    gld16(q8g + ((size_t)(bh*SEQ) + i0)*HD + tid*16, q8s + tid*16);

  { // stage conv v window [d][i0-1 .. i0+32]
    int d = tid >> 2, part = tid & 3;
    const f16* vrow = vTg + ((size_t)(bh*HD) + d)*SEQ;
#pragma unroll
    for (int e = 0; e < 9; ++e) {
      int ss = part*9 + e;
      if (ss < 34) {
        int s = i0 - 1 + ss;
        vconv[d*34 + ss] = (s >= 0 && s < SEQ) ? vrow[s] : (f16)0.0f;
      }
    }
  }
  __syncthreads();

  // q rows {iL+8n} into regs (64 u32), one-time read
  unsigned qr[4][16];
#pragma unroll
  for (int n = 0; n < 4; ++n)
#pragma unroll
    for (int c4 = 0; c4 < 4; ++c4) {
      uint4 t = *(const uint4*)&q8s[(iL + 8*n)*64 + c4*16];
      qr[n][c4*4+0] = t.x; qr[n][c4*4+1] = t.y; qr[n][c4*4+2] = t.z; qr[n][c4*4+3] = t.w;
    }

  float rs[4] = {0.f, 0.f, 0.f, 0.f};
  floatx4 pacc[2] = {};

  for (int jb = 0; jb < 8; ++jb) {
    const int j0 = jb * 128;
    __syncthreads();                       // prev iter done with k8s/vTs/sfrag
#pragma unroll
    for (int r = 0; r < 2; ++r) {          // k tile, group-swizzled store:
      int slot = r*256 + tid;              // LDS row `row` group c holds global group c^((row>>2)&3)
      int row = slot >> 2, c = slot & 3, g = c ^ ((row >> 2) & 3);
      gld16(k8g + ((size_t)(bh*SEQ) + j0)*HD + row*64 + g*16, k8s + slot*16);
    }
#pragma unroll
    for (int r = 0; r < 4; ++r) {          // vT tile [64][128], xor swizzle
      int slot = r*256 + tid;
      int d = slot >> 4, c = slot & 15, sc = c ^ (d & 7);
      gld16(vTg + ((size_t)(bh*HD) + d)*SEQ + j0 + sc*8, vTs + slot*8);
    }
    __syncthreads();                       // staging complete

    // ---- phase 1: SAD distances, 4 rows x 4 keys per thread ----
    unsigned sacc[4][4] = {};
#pragma unroll
    for (int c4 = 0; c4 < 4; ++c4) {
      uint4 kk[4];
#pragma unroll
      for (int jj = 0; jj < 4; ++jj)       // logical group c4 lives at LDS group c4^(jt&3)
        kk[jj] = *(const uint4*)&k8s[(jt*4 + jj)*64 + ((c4 ^ (jt & 3))*16)];
#pragma unroll
      for (int n = 0; n < 4; ++n)
#pragma unroll
        for (int jj = 0; jj < 4; ++jj) {
          sacc[n][jj] = sadU8(qr[n][c4*4+0], kk[jj].x, sacc[n][jj]);
          sacc[n][jj] = sadU8(qr[n][c4*4+1], kk[jj].y, sacc[n][jj]);
          sacc[n][jj] = sadU8(qr[n][c4*4+2], kk[jj].z, sacc[n][jj]);
          sacc[n][jj] = sadU8(qr[n][c4*4+3], kk[jj].w, sacc[n][jj]);
        }
    }
    // kern = exp(-dist/16) -> exp2(-sad*log2e/256); write A-frag layout:
    // key = jt*4+jj: chunk ks = jt>>3(=wave), laneL = rowL + 16*((jt>>1)&3),
    // elem = (jt&1)*4+jj; rowL = iL+8*(n&1), mt = n>>1.
#pragma unroll
    for (int n = 0; n < 4; ++n) {
      half4v sv;
#pragma unroll
      for (int jj = 0; jj < 4; ++jj) {
        float sf = exp2f(-0.0056355275f * (float)sacc[n][jj]);
        rs[n] += sf;
        sv[jj] = (f16)sf;
      }
      *(half4v*)&sfrag[(((n>>1)*4 + (jt>>3))*64 + iL + 8*(n&1) + 16*((jt>>1)&3))*8
                       + (jt&1)*4] = sv;
    }
    __syncthreads();                       // scores ready

    // ---- phase 2: PV via MFMA; wave = (m-tile mtw, d-half dh) ----
#pragma unroll
    for (int ks = 0; ks < 4; ++ks) {
      half8 a = *(const half8*)&sfrag[((mtw*4 + ks)*64 + lane)*8];
#pragma unroll
      for (int nt = 0; nt < 2; ++nt) {
        int d = dh*32 + nt*16 + li;
        int kc = ks*4 + lq;
        half8 bfr = *(const half8*)&vTs[d*128 + (kc ^ (d & 7))*8];
        pacc[nt] = __builtin_amdgcn_mfma_f32_16x16x32_f16(a, bfr, pacc[nt], 0, 0, 0);
      }
    }
  }

  // rowsum: reduce over jt within wave (lane bits 3..5), then LDS atomics
#pragma unroll
  for (int n = 0; n < 4; ++n) {
    rs[n] += __shfl_xor(rs[n], 8, 64);
    rs[n] += __shfl_xor(rs[n], 16, 64);
    rs[n] += __shfl_xor(rs[n], 32, 64);
  }
  if (lane < 8) {
#pragma unroll
    for (int n = 0; n < 4; ++n) atomicAdd(&rowsum[lane + 8*n], rs[n]);
  }
  __syncthreads();

  // epilogue: normalize + depthwise conv + store y16 [b,s,h*64+d]
  const int b = bh >> 4, h = bh & 15;
#pragma unroll
  for (int nt = 0; nt < 2; ++nt) {
    int d = dh*32 + nt*16 + li;
    int c = h*64 + d;
    float w0 = dwcw[c*3+0], w1 = dwcw[c*3+1], w2 = dwcw[c*3+2], cb = dwcb[c];
#pragma unroll
    for (int r = 0; r < 4; ++r) {
      int ii = mtw*16 + lq*4 + r;
      float val = pacc[nt][r] / rowsum[ii];
      val += w0*(float)vconv[d*34 + ii] + w1*(float)vconv[d*34 + ii + 1]
           + w2*(float)vconv[d*34 + ii + 2] + cb;
      int s = i0 + ii;
      y16[((size_t)(b*SEQ + s))*DIMC + c] = (f16)val;
    }
  }
}

extern "C" void kernel_launch(void* const* d_in, const int* in_sizes, int n_in,
                              void* d_out, int out_size, void* d_ws, size_t ws_size,
                              hipStream_t stream) {
  const float* x      = (const float*)d_in[0];
  const float* qkv_w  = (const float*)d_in[1];
  const float* qkv_b  = (const float*)d_in[2];
  const float* proj_w = (const float*)d_in[3];
  const float* proj_b = (const float*)d_in[4];
  const float* dwc_w  = (const float*)d_in[5];
  const float* dwc_b  = (const float*)d_in[6];
  float* out = (float*)d_out;

  char* ws = (char*)d_ws;
  f16* x16  = (f16*)(ws);                         //  4 MB
  f16* wq16 = (f16*)(ws + (4ll<<20));             //  6 MB
  f16* wp16 = (f16*)(ws + (10ll<<20));            //  2 MB
  unsigned char* q8 = (unsigned char*)(ws + (12ll<<20));  // 2 MB
  unsigned char* k8 = (unsigned char*)(ws + (14ll<<20));  // 2 MB
  f16* vT   = (f16*)(ws + (16ll<<20));            //  4 MB
  f16* y16  = (f16*)(ws + (20ll<<20));            //  4 MB (total 24 MB)

  cvt_kernel<<<1536, 256, 0, stream>>>(x, qkv_w, proj_w, x16, wq16, wp16);
  // gemm0: 128x128 tile, BK=128 (8 K-iters) — grid 24x16 = 384 blocks
  gemm_kernel<128,128,128,2,0><<<dim3(24, 16), 256, 0, stream>>>(x16, wq16, qkv_b, q8, k8, vT, nullptr, DIMC);
  attn_kernel<<<dim3(32, 32), 256, 0, stream>>>(q8, k8, vT, dwc_w, dwc_b, y16);
  // gemm1: 64x64 tile, BK=128 — grid 16x32 = 512 blocks
  gemm_kernel<64,64,128,4,1><<<dim3(16, 32), 256, 0, stream>>>(y16, wp16, proj_b, nullptr, nullptr, nullptr, out, DIMC);
}

// Round 13
// 150.697 us; speedup vs baseline: 1.0485x; 1.0485x over previous
//
#include <hip/hip_runtime.h>

#define DIMC 1024
#define HEADS 16
#define HD 64
#define BATCH 2
#define SEQ 1024
#define NQKV 3072

typedef _Float16 f16;
typedef _Float16 half8 __attribute__((ext_vector_type(8)));
typedef _Float16 half4v __attribute__((ext_vector_type(4)));
typedef float floatx4 __attribute__((ext_vector_type(4)));

__device__ __forceinline__ void gld16(const void* g, void* l) {
  __builtin_amdgcn_global_load_lds((const __attribute__((address_space(1))) void*)g,
                                   (__attribute__((address_space(3))) void*)l, 16, 0, 0);
}

__device__ __forceinline__ unsigned sadU8(unsigned a, unsigned b, unsigned c) {
#if __has_builtin(__builtin_amdgcn_sad_u8)
  return __builtin_amdgcn_sad_u8(a, b, c);
#else
  unsigned d;
  asm("v_sad_u8 %0, %1, %2, %3" : "=v"(d) : "v"(a), "v"(b), "v"(c));
  return d;
#endif
}

// ---------------- f32 -> f16 casts (x, qkv_w, proj_w), 4 float4/thread ----------------
__global__ __launch_bounds__(256) void cvt_kernel(
    const float* __restrict__ x, const float* __restrict__ wq, const float* __restrict__ wp,
    f16* __restrict__ x16, f16* __restrict__ wq16, f16* __restrict__ wp16)
{
  int bid = blockIdx.x;
  const float* src; f16* dst; int base;
  if (bid < 512)        { src = x;  dst = x16;  base = bid; }
  else if (bid < 1280)  { src = wq; dst = wq16; base = bid - 512; }
  else                  { src = wp; dst = wp16; base = bid - 1280; }
  long long i0 = (long long)base*1024 + threadIdx.x;
#pragma unroll
  for (int k2 = 0; k2 < 4; ++k2) {
    long long i = i0 + k2*256;   // float4 index, coalesced
    float4 v = ((const float4*)src)[i];
    half4v h; h[0]=(f16)v.x; h[1]=(f16)v.y; h[2]=(f16)v.z; h[3]=(f16)v.w;
    *(half4v*)(dst + i*4) = h;
  }
}

// ---------------- TM x TN f16 MFMA GEMM (BK-deep K-tiles), C = A * Bw^T + bias ----
// MODE 0: QKV -> q8/k8 (u8 quant, [b,h,s,d]) and vT (f16, [b,h,d,s])
// MODE 1: proj -> f32 out [t, f]
template<int TM, int TN, int BK, int MW, int MODE>
__global__ __launch_bounds__(256, MW) void gemm_kernel(
    const f16* __restrict__ A, const f16* __restrict__ Bw, const float* __restrict__ bias,
    unsigned char* __restrict__ q8, unsigned char* __restrict__ k8, f16* __restrict__ vT,
    float* __restrict__ outp, int K)
{
  constexpr int MT = TM / 32;   // m-subtiles per wave
  constexpr int NT = TN / 32;   // n-subtiles per wave
  constexpr int G  = BK / 8;    // 16B groups per LDS row
  __shared__ f16 As[TM*BK];
  __shared__ f16 Bs[TN*BK];
  const int tid = threadIdx.x;
  const int wave = tid >> 6, lane = tid & 63;
  const int lq = lane >> 4, li = lane & 15;
  const int m0 = blockIdx.y * TM, n0 = blockIdx.x * TN;
  const int wm = (wave & 1) * (TM/2), wn = (wave >> 1) * (TN/2);
  floatx4 acc[MT][NT] = {};

  const int kIters = K / BK;
  for (int kt = 0; kt < kIters; ++kt) {
    __syncthreads();
#pragma unroll
    for (int r = 0; r < TM*BK/2048; ++r) {
      int slot = r*256 + tid;
      int row = slot / G, c = slot % G, g = c ^ (row & (G-1));
      gld16(A + (size_t)(m0+row)*K + kt*BK + g*8, As + slot*8);
    }
#pragma unroll
    for (int r = 0; r < TN*BK/2048; ++r) {
      int slot = r*256 + tid;
      int row = slot / G, c = slot % G, g = c ^ (row & (G-1));
      gld16(Bw + (size_t)(n0+row)*K + kt*BK + g*8, Bs + slot*8);
    }
    __syncthreads();
#pragma unroll
    for (int ks = 0; ks < BK/32; ++ks) {
      half8 af[MT], bf[NT];
      int kc = ks*4 + lq;
#pragma unroll
      for (int t = 0; t < MT; ++t) {
        int am = wm + t*16 + li;
        af[t] = *(const half8*)&As[am*BK + (kc ^ (am & (G-1)))*8];
      }
#pragma unroll
      for (int t = 0; t < NT; ++t) {
        int bn = wn + t*16 + li;
        bf[t] = *(const half8*)&Bs[bn*BK + (kc ^ (bn & (G-1)))*8];
      }
#pragma unroll
      for (int mt = 0; mt < MT; ++mt)
#pragma unroll
        for (int nt = 0; nt < NT; ++nt)
          acc[mt][nt] = __builtin_amdgcn_mfma_f32_16x16x32_f16(af[mt], bf[nt], acc[mt][nt], 0, 0, 0);
    }
  }

#pragma unroll
  for (int mt = 0; mt < MT; ++mt) {
#pragma unroll
    for (int nt = 0; nt < NT; ++nt) {
      int f = n0 + wn + nt*16 + li;                 // output feature (col, from B)
      float bb = bias[f];
      if (MODE == 0) {
        int which = f >> 10, cc = f & 1023, h = cc >> 6, d = cc & 63;
        int t0 = m0 + wm + mt*16 + lq*4;            // token (row, from A), 4 consecutive
        int b = t0 >> 10, s0 = t0 & 1023;
        if (which == 2) {
          half4v hv;
#pragma unroll
          for (int r = 0; r < 4; ++r) hv[r] = (f16)(acc[mt][nt][r] + bb);
          *(half4v*)&vT[((size_t)((b*HEADS + h)*HD + d))*SEQ + s0] = hv;
        } else {
          unsigned char* dst = (which == 0) ? q8 : k8;
#pragma unroll
          for (int r = 0; r < 4; ++r) {
            float v = acc[mt][nt][r] + bb;
            int u = (int)floorf(v * 16.0f + 128.5f);
            u = u < 0 ? 0 : (u > 255 ? 255 : u);
            dst[((size_t)((b*HEADS + h)*SEQ + s0 + r))*HD + d] = (unsigned char)u;
          }
        }
      } else {
#pragma unroll
        for (int r = 0; r < 4; ++r) {
          int t = m0 + wm + mt*16 + lq*4 + r;
          outp[(size_t)t*DIMC + f] = acc[mt][nt][r] + bb;
        }
      }
    }
  }
}

// ---------------- Laplacian attention + depthwise conv, y16 out ----------------
// R13 = R8 attn VERBATIM (best measured: 45.5 us; survived 8 structural challenges)
// + XCD-aware block swizzle: lin = bx + 16*by; bh = (lin&7)*4 + ((lin>>3)&3),
// i0 = (lin>>5)*64. Each XCD exclusively owns 4 bh-groups (~1MB << 4MB L2), so
// the 16 blocks sharing one bh's k8/vT hit L2 instead of L3.
__global__ __launch_bounds__(256, 2) void attn_kernel(
    const unsigned char* __restrict__ q8g, const unsigned char* __restrict__ k8g,
    const f16* __restrict__ vTg, const float* __restrict__ dwcw, const float* __restrict__ dwcb,
    f16* __restrict__ y16)
{
  __shared__ unsigned char q8s[64*64];   //  4KB
  __shared__ unsigned char k8s[128*64];  //  8KB
  __shared__ f16 vTs[64*128];            // 16KB  [d][j] swizzled
  __shared__ f16 sfrag[16*64*8];         // 16KB  scores in MFMA A-frag layout
  __shared__ float rspart[64*16];        //  4KB
  __shared__ float rowsum[64];
  __shared__ f16 vconv[64*66];           // 8.25KB v window for conv

  const int tid = threadIdx.x;
  const int lin = blockIdx.x + 16 * blockIdx.y;
  const int bh = (lin & 7) * 4 + ((lin >> 3) & 3);   // XCD-grouped head index
  const int i0 = (lin >> 5) * 64;
  const int lane = tid & 63, wave = tid >> 6;
  const int lq = lane >> 4, li = lane & 15;
  const int iL = tid & 15, jt = tid >> 4;       // phase-1 mapping
  const int ksj = jt >> 2, qj = jt & 3;

  { // stage q tile: 64 rows x 64B
    gld16(q8g + ((size_t)(bh*SEQ) + i0)*HD + tid*16, q8s + tid*16);
  }
  { // stage conv v window [d][i0-1 .. i0+64]
    int d = tid >> 2, part = tid & 3;
    const f16* vrow = vTg + ((size_t)(bh*HD) + d)*SEQ;
#pragma unroll
    for (int e = 0; e < 17; ++e) {
      int ss = part*17 + e;
      if (ss < 66) {
        int s = i0 - 1 + ss;
        vconv[d*66 + ss] = (s >= 0 && s < SEQ) ? vrow[s] : (f16)0.0f;
      }
    }
  }
  __syncthreads();

  // q rows {iL, iL+16, iL+32, iL+48} into regs (64 u32)
  unsigned qr[4][16];
#pragma unroll
  for (int n = 0; n < 4; ++n)
#pragma unroll
    for (int c4 = 0; c4 < 4; ++c4) {
      uint4 t = *(const uint4*)&q8s[(iL + n*16)*64 + c4*16];
      qr[n][c4*4+0] = t.x; qr[n][c4*4+1] = t.y; qr[n][c4*4+2] = t.z; qr[n][c4*4+3] = t.w;
    }

  float rs[4] = {0.f, 0.f, 0.f, 0.f};
  floatx4 pacc[2][2] = {};
  const int mtb = (wave & 1) * 2, ntb = (wave >> 1) * 2;

  for (int jb = 0; jb < 8; ++jb) {
    const int j0 = jb * 128;
    __syncthreads();                       // prev iter done with k8s/vTs/sfrag
#pragma unroll
    for (int r = 0; r < 2; ++r) {          // k tile: 128 rows x 64B
      int slot = r*256 + tid;
      gld16(k8g + ((size_t)(bh*SEQ) + j0)*HD + slot*16, k8s + slot*16);
    }
#pragma unroll
    for (int r = 0; r < 4; ++r) {          // vT tile [64][128], xor swizzle
      int slot = r*256 + tid;
      int d = slot >> 4, c = slot & 15, sc = c ^ (d & 7);
      gld16(vTg + ((size_t)(bh*HD) + d)*SEQ + j0 + sc*8, vTs + slot*8);
    }
    __syncthreads();                       // staging complete

    // ---- phase 1: SAD distances, 4 i x 8 j per thread ----
    unsigned sacc[4][8] = {};
#pragma unroll
    for (int c4 = 0; c4 < 4; ++c4) {
      uint4 kk[8];
#pragma unroll
      for (int jj = 0; jj < 8; ++jj)
        kk[jj] = *(const uint4*)&k8s[(jt*8 + jj)*64 + c4*16];   // 16-lane broadcast
#pragma unroll
      for (int n = 0; n < 4; ++n)
#pragma unroll
        for (int jj = 0; jj < 8; ++jj) {
          sacc[n][jj] = sadU8(qr[n][c4*4+0], kk[jj].x, sacc[n][jj]);
          sacc[n][jj] = sadU8(qr[n][c4*4+1], kk[jj].y, sacc[n][jj]);
          sacc[n][jj] = sadU8(qr[n][c4*4+2], kk[jj].z, sacc[n][jj]);
          sacc[n][jj] = sadU8(qr[n][c4*4+3], kk[jj].w, sacc[n][jj]);
        }
    }
    // kern = exp(-dist/16), dist = sad/16  ->  exp2(-sad * log2(e)/256)
#pragma unroll
    for (int n = 0; n < 4; ++n) {
      half8 sv;
#pragma unroll
      for (int jj = 0; jj < 8; ++jj) {
        float sf = exp2f(-0.0056355275f * (float)sacc[n][jj]);
        rs[n] += sf;
        sv[jj] = (f16)sf;
      }
      // A-frag layout: slot = (mt*4 + ks)*64 + lane, lane = qj*16 + iL (lane-contiguous)
      *(half8*)&sfrag[((n*4 + ksj)*64 + qj*16 + iL)*8] = sv;
    }
    __syncthreads();                       // scores ready

    // ---- phase 2: PV via MFMA, wave tile 32i x 32d ----
#pragma unroll
    for (int ks = 0; ks < 4; ++ks) {
      half8 a0 = *(const half8*)&sfrag[(((mtb+0)*4 + ks)*64 + lane)*8];
      half8 a1 = *(const half8*)&sfrag[(((mtb+1)*4 + ks)*64 + lane)*8];
#pragma unroll
      for (int nt = 0; nt < 2; ++nt) {
        int d = (ntb + nt)*16 + li;
        int kc = ks*4 + lq;
        half8 bfr = *(const half8*)&vTs[d*128 + (kc ^ (d & 7))*8];
        pacc[0][nt] = __builtin_amdgcn_mfma_f32_16x16x32_f16(a0, bfr, pacc[0][nt], 0, 0, 0);
        pacc[1][nt] = __builtin_amdgcn_mfma_f32_16x16x32_f16(a1, bfr, pacc[1][nt], 0, 0, 0);
      }
    }
  }

  // rowsum reduction across the 16 j-slices
#pragma unroll
  for (int n = 0; n < 4; ++n) rspart[(iL + n*16)*16 + jt] = rs[n];
  __syncthreads();
  if (tid < 64) {
    float s = 0.f;
#pragma unroll
    for (int t = 0; t < 16; ++t) s += rspart[tid*16 + t];
    rowsum[tid] = s + 1e-6f;
  }
  __syncthreads();

  // epilogue: normalize + depthwise conv + store y16 [b,s,h*64+d]
  const int b = bh >> 4, h = bh & 15;
#pragma unroll
  for (int nt = 0; nt < 2; ++nt) {
    int d = (ntb + nt)*16 + li;
    int c = h*64 + d;
    float w0 = dwcw[c*3+0], w1 = dwcw[c*3+1], w2 = dwcw[c*3+2], cb = dwcb[c];
#pragma unroll
    for (int mt = 0; mt < 2; ++mt)
#pragma unroll
      for (int r = 0; r < 4; ++r) {
        int ii = (mtb + mt)*16 + lq*4 + r;
        float val = pacc[mt][nt][r] / rowsum[ii];
        val += w0*(float)vconv[d*66 + ii] + w1*(float)vconv[d*66 + ii + 1]
             + w2*(float)vconv[d*66 + ii + 2] + cb;
        int s = i0 + ii;
        y16[((size_t)(b*SEQ + s))*DIMC + c] = (f16)val;
      }
  }
}

extern "C" void kernel_launch(void* const* d_in, const int* in_sizes, int n_in,
                              void* d_out, int out_size, void* d_ws, size_t ws_size,
                              hipStream_t stream) {
  const float* x      = (const float*)d_in[0];
  const float* qkv_w  = (const float*)d_in[1];
  const float* qkv_b  = (const float*)d_in[2];
  const float* proj_w = (const float*)d_in[3];
  const float* proj_b = (const float*)d_in[4];
  const float* dwc_w  = (const float*)d_in[5];
  const float* dwc_b  = (const float*)d_in[6];
  float* out = (float*)d_out;

  char* ws = (char*)d_ws;
  f16* x16  = (f16*)(ws);                         //  4 MB
  f16* wq16 = (f16*)(ws + (4ll<<20));             //  6 MB
  f16* wp16 = (f16*)(ws + (10ll<<20));            //  2 MB
  unsigned char* q8 = (unsigned char*)(ws + (12ll<<20));  // 2 MB
  unsigned char* k8 = (unsigned char*)(ws + (14ll<<20));  // 2 MB
  f16* vT   = (f16*)(ws + (16ll<<20));            //  4 MB
  f16* y16  = (f16*)(ws + (20ll<<20));            //  4 MB (total 24 MB)

  cvt_kernel<<<1536, 256, 0, stream>>>(x, qkv_w, proj_w, x16, wq16, wp16);
  // gemm0: 128x128 tile, BK=128 (8 K-iters) — grid 24x16 = 384 blocks
  gemm_kernel<128,128,128,2,0><<<dim3(24, 16), 256, 0, stream>>>(x16, wq16, qkv_b, q8, k8, vT, nullptr, DIMC);
  attn_kernel<<<dim3(16, 32), 256, 0, stream>>>(q8, k8, vT, dwc_w, dwc_b, y16);
  // gemm1: 64x64 tile, BK=128 — grid 16x32 = 512 blocks
  gemm_kernel<64,64,128,4,1><<<dim3(16, 32), 256, 0, stream>>>(y16, wp16, proj_b, nullptr, nullptr, nullptr, out, DIMC);
}